// Round 3
// baseline (604.997 us; speedup 1.0000x reference)
//
#include <hip/hip_runtime.h>
#include <hip/hip_bf16.h>

typedef float f32x4 __attribute__((ext_vector_type(4)));
typedef short bf16x8 __attribute__((ext_vector_type(8)));

__device__ inline unsigned short f2bf(float x) {
    __hip_bfloat16 h = __float2bfloat16(x);
    return *reinterpret_cast<unsigned short*>(&h);
}

// ---------------------------------------------------------------------------
// 3x3 VALID conv, stride 1, fused BN-sum reduction (atomicAdd per channel).
// Block = 16x16 spatial tile, grid.z = oc. No early returns (barrier safety).
// ---------------------------------------------------------------------------
__global__ void conv3x3_kernel(const float* __restrict__ src, int Cin, int H, int W,
                               const float* __restrict__ w, const float* __restrict__ b,
                               float* __restrict__ dst, int OH, int OW,
                               float* __restrict__ bn_accum) {
    extern __shared__ float lds[];           // [Cin*324] x | [Cin*9] w | [512] red
    float* xs  = lds;
    float* ws  = lds + Cin * 324;
    float* red = ws + Cin * 9;
    const int oc  = blockIdx.z;
    const int tx0 = blockIdx.x * 16, ty0 = blockIdx.y * 16;
    const int tid = threadIdx.y * 16 + threadIdx.x;

    for (int i = tid; i < Cin * 9; i += 256) ws[i] = w[oc * Cin * 9 + i];
    {
        int ic = 0, rem = tid;               // tid < 256 < 324
        for (int i = tid; i < Cin * 324; i += 256) {
            int r  = rem / 18;
            int cc = rem - r * 18;
            int y = ty0 + r, x = tx0 + cc;
            xs[i] = (y < H && x < W) ? src[((size_t)ic * H + y) * W + x] : 0.f;
            rem += 256;
            if (rem >= 324) { rem -= 324; ++ic; }
        }
    }
    __syncthreads();

    const int ox = tx0 + threadIdx.x, oy = ty0 + threadIdx.y;
    const bool valid = (ox < OW && oy < OH);
    float acc = b[oc];
    for (int ic = 0; ic < Cin; ++ic) {
        const float* xp = &xs[ic * 324 + threadIdx.y * 18 + threadIdx.x];
        const float* wp = &ws[ic * 9];
        #pragma unroll
        for (int kh = 0; kh < 3; ++kh)
            #pragma unroll
            for (int kw = 0; kw < 3; ++kw)
                acc = fmaf(xp[kh * 18 + kw], wp[kh * 3 + kw], acc);
    }
    if (valid) dst[((size_t)oc * OH + oy) * OW + ox] = acc;

    // fused BN partial sums
    float vs = valid ? acc : 0.f;
    red[tid]       = vs;
    red[256 + tid] = vs * vs;
    __syncthreads();
    for (int off = 128; off > 0; off >>= 1) {
        if (tid < off) {
            red[tid]       += red[tid + off];
            red[256 + tid] += red[256 + tid + off];
        }
        __syncthreads();
    }
    if (tid == 0) {
        atomicAdd(&bn_accum[oc * 2],     red[0]);
        atomicAdd(&bn_accum[oc * 2 + 1], red[256]);
    }
}

// ---------------------------------------------------------------------------
// Finalize BN: sums -> (inv = g/sqrt(var+eps), shift = b - mean*inv).
// ---------------------------------------------------------------------------
__global__ void bn_final_kernel(const float* __restrict__ sums, int C, int spatial,
                                const float* __restrict__ g, const float* __restrict__ bb,
                                float* __restrict__ inv_shift) {
    int c = threadIdx.x;
    if (c >= C) return;
    float m   = sums[c * 2] / (float)spatial;
    float var = sums[c * 2 + 1] / (float)spatial - m * m;
    float inv = g[c] * rsqrtf(var + 1e-5f);
    inv_shift[c * 2]     = inv;
    inv_shift[c * 2 + 1] = bb[c] - m * inv;
}

// ---------------------------------------------------------------------------
// Fused BN-apply + ReLU + 2x2/2 max-pool (VALID).
// ---------------------------------------------------------------------------
__global__ void bn_pool_kernel(const float* __restrict__ src,
                               const float* __restrict__ inv_shift,
                               int H, int W, int OH, int OW, int C,
                               float* __restrict__ dst) {
    int i = blockIdx.x * blockDim.x + threadIdx.x;
    if (i >= C * OH * OW) return;
    int ox = i % OW;
    int oy = (i / OW) % OH;
    int c  = i / (OW * OH);
    float inv = inv_shift[c * 2], sh = inv_shift[c * 2 + 1];
    const float* p = src + ((size_t)c * H + 2 * oy) * W + 2 * ox;
    float a = fmaxf(fmaf(p[0],     inv, sh), 0.f);
    float b = fmaxf(fmaf(p[1],     inv, sh), 0.f);
    float d = fmaxf(fmaf(p[W],     inv, sh), 0.f);
    float e = fmaxf(fmaf(p[W + 1], inv, sh), 0.f);
    dst[i] = fmaxf(fmaxf(a, b), fmaxf(d, e));
}

// ---------------------------------------------------------------------------
// 1x1-conv QKV projection. q,k fp32 (stride NP); v bf16 (stride NP).
// ---------------------------------------------------------------------------
__global__ void qkv_proj_kernel(const float* __restrict__ xf, int N, int NP, int C, int Cqk,
                                const float* __restrict__ qw, const float* __restrict__ qb,
                                const float* __restrict__ kw, const float* __restrict__ kb,
                                const float* __restrict__ vw, const float* __restrict__ vb,
                                float* __restrict__ q, float* __restrict__ k,
                                unsigned short* __restrict__ v) {
    constexpr int OCG = 8;
    __shared__ float wl[OCG * 64 + OCG];
    const int g0 = blockIdx.y * OCG;
    const int tid = threadIdx.x;
    for (int i = tid; i < OCG * C; i += blockDim.x) {
        int o = i / C, cc = i % C;
        int oc = g0 + o;
        const float* wsrc = (oc < Cqk) ? (qw + oc * C)
                          : (oc < 2 * Cqk) ? (kw + (oc - Cqk) * C)
                          : (vw + (oc - 2 * Cqk) * C);
        wl[o * C + cc] = wsrc[cc];
    }
    if (tid < OCG) {
        int oc = g0 + tid;
        wl[OCG * C + tid] = (oc < Cqk) ? qb[oc]
                          : (oc < 2 * Cqk) ? kb[oc - Cqk]
                          : vb[oc - 2 * Cqk];
    }
    __syncthreads();
    int n = blockIdx.x * blockDim.x + tid;
    if (n >= N) return;
    float acc[OCG];
    #pragma unroll
    for (int o = 0; o < OCG; ++o) acc[o] = wl[OCG * C + o];
    for (int c = 0; c < C; ++c) {
        float xv = xf[(size_t)c * N + n];
        #pragma unroll
        for (int o = 0; o < OCG; ++o) acc[o] = fmaf(xv, wl[o * C + c], acc[o]);
    }
    #pragma unroll
    for (int o = 0; o < OCG; ++o) {
        int oc = g0 + o;
        if (oc < Cqk)            q[(size_t)oc * NP + n] = acc[o];
        else if (oc < 2 * Cqk)   k[(size_t)(oc - Cqk) * NP + n] = acc[o];
        else                     v[(size_t)(oc - 2 * Cqk) * NP + n] = f2bf(acc[o]);
    }
}

// ---------------------------------------------------------------------------
// MFMA flash attention v2: NO LDS, NO barriers. K (fp32) and V (bf16) read
// directly from global (L2-resident, heavy reuse). q pre-scaled by log2e so
// p = exp2(e) is a single v_exp_f32. Each lane: query = lane&15, keys 8g+j.
// m0 and all full-chunk mt are multiples of 32; NP is N rounded to 32 so
// tail loads stay in-bounds (masked out of lsum/pfrag).
// ---------------------------------------------------------------------------
template <int CQK, int CV>
__launch_bounds__(256)
__global__ void flash_mfma_kernel(const float* __restrict__ q,
                                  const float* __restrict__ k,
                                  const unsigned short* __restrict__ v,
                                  int N, int NP, int chunk,
                                  float* __restrict__ l_part,
                                  float* __restrict__ acc_part) {
    const int tid  = threadIdx.x;
    const int wave = tid >> 6;
    const int lane = tid & 63;
    const int row  = lane & 15;     // query row (A-frag) / ch col (D-frag)
    const int g    = lane >> 4;
    const int s    = blockIdx.y;
    const int m0   = s * chunk;
    const int m1   = min(N, m0 + chunk);
    const int qb   = blockIdx.x * 64 + wave * 16;
    const int n    = qb + row;

    float qr[CQK];
    #pragma unroll
    for (int c = 0; c < CQK; ++c)
        qr[c] = (n < N) ? q[(size_t)c * NP + n] * 1.44269504f : 0.f;

    const float* kb[CQK];
    #pragma unroll
    for (int c = 0; c < CQK; ++c) kb[c] = k + (size_t)c * NP + 8 * g;
    const unsigned short* vb[CV / 16];
    #pragma unroll
    for (int f = 0; f < CV / 16; ++f) vb[f] = v + (size_t)(f * 16 + row) * NP + 8 * g;

    f32x4 acc[CV / 16];
    #pragma unroll
    for (int f = 0; f < CV / 16; ++f) acc[f] = (f32x4){0.f, 0.f, 0.f, 0.f};
    float lsum = 0.f;

    const int nfull = (m1 - m0) & ~31;
    int mt = m0;
    for (; mt < m0 + nfull; mt += 32) {
        f32x4 e0 = (f32x4){0.f, 0.f, 0.f, 0.f};
        f32x4 e1 = (f32x4){0.f, 0.f, 0.f, 0.f};
        #pragma unroll
        for (int c = 0; c < CQK; ++c) {
            f32x4 ka = *(const f32x4*)(kb[c] + mt);
            f32x4 kc = *(const f32x4*)(kb[c] + mt + 4);
            e0 += qr[c] * ka;
            e1 += qr[c] * kc;
        }
        bf16x8 pfrag;
        #pragma unroll
        for (int j = 0; j < 4; ++j) {
            float p = exp2f(e0[j]); lsum += p; pfrag[j] = (short)f2bf(p);
        }
        #pragma unroll
        for (int j = 0; j < 4; ++j) {
            float p = exp2f(e1[j]); lsum += p; pfrag[4 + j] = (short)f2bf(p);
        }
        #pragma unroll
        for (int f = 0; f < CV / 16; ++f) {
            bf16x8 vf = *(const bf16x8*)(vb[f] + mt);
            acc[f] = __builtin_amdgcn_mfma_f32_16x16x32_bf16(pfrag, vf, acc[f], 0, 0, 0);
        }
    }
    if (mt < m1) {   // masked tail chunk
        f32x4 e0 = (f32x4){0.f, 0.f, 0.f, 0.f};
        f32x4 e1 = (f32x4){0.f, 0.f, 0.f, 0.f};
        #pragma unroll
        for (int c = 0; c < CQK; ++c) {
            f32x4 ka = *(const f32x4*)(kb[c] + mt);
            f32x4 kc = *(const f32x4*)(kb[c] + mt + 4);
            e0 += qr[c] * ka;
            e1 += qr[c] * kc;
        }
        bf16x8 pfrag;
        #pragma unroll
        for (int j = 0; j < 4; ++j) {
            bool ok = (mt + 8 * g + j) < m1;
            float p = ok ? exp2f(e0[j]) : 0.f;
            lsum += p; pfrag[j] = (short)f2bf(p);
        }
        #pragma unroll
        for (int j = 0; j < 4; ++j) {
            bool ok = (mt + 8 * g + 4 + j) < m1;
            float p = ok ? exp2f(e1[j]) : 0.f;
            lsum += p; pfrag[4 + j] = (short)f2bf(p);
        }
        #pragma unroll
        for (int f = 0; f < CV / 16; ++f) {
            bf16x8 vf = *(const bf16x8*)(vb[f] + mt);
            acc[f] = __builtin_amdgcn_mfma_f32_16x16x32_bf16(pfrag, vf, acc[f], 0, 0, 0);
        }
    }

    lsum += __shfl_xor(lsum, 16, 64);
    lsum += __shfl_xor(lsum, 32, 64);
    if (g == 0 && n < N) l_part[(size_t)s * N + n] = lsum;

    #pragma unroll
    for (int f = 0; f < CV / 16; ++f) {
        #pragma unroll
        for (int r2 = 0; r2 < 4; ++r2) {
            int nq = qb + 4 * g + r2;
            if (nq < N)
                acc_part[((size_t)s * N + nq) * CV + f * 16 + row] = acc[f][r2];
        }
    }
}

// ---------------------------------------------------------------------------
// Combine key-split partials. Thread-per-n, 16 cv channels in registers:
// acc reads are 64B-contiguous per lane, out/res accesses coalesced per cv.
// grid = (ceil(N/256), CV/16).
// ---------------------------------------------------------------------------
__global__ void combine_kernel(const float* __restrict__ acc_part,
                               const float* __restrict__ l_part,
                               int nsplit, int N, int CV,
                               const float* __restrict__ gamma,
                               const float* __restrict__ x_res,
                               float* __restrict__ out) {
    int n = blockIdx.x * blockDim.x + threadIdx.x;
    if (n >= N) return;
    int cv0 = blockIdx.y * 16;
    float l = 0.f;
    for (int s = 0; s < nsplit; ++s) l += l_part[(size_t)s * N + n];
    f32x4 a[4];
    #pragma unroll
    for (int t = 0; t < 4; ++t) a[t] = (f32x4){0.f, 0.f, 0.f, 0.f};
    for (int s = 0; s < nsplit; ++s) {
        const float* p = acc_part + ((size_t)s * N + n) * CV + cv0;
        #pragma unroll
        for (int t = 0; t < 4; ++t) a[t] += *(const f32x4*)(p + 4 * t);
    }
    float gs = gamma[0] / l;
    #pragma unroll
    for (int t = 0; t < 4; ++t)
        #pragma unroll
        for (int u = 0; u < 4; ++u) {
            int cv = cv0 + 4 * t + u;
            out[(size_t)cv * N + n] = fmaf(gs, a[t][u], x_res[(size_t)cv * N + n]);
        }
}

// ---------------------------------------------------------------------------
// FC: out[50] = h @ W^T + b.
// ---------------------------------------------------------------------------
__global__ void fc_partial_kernel(const float* __restrict__ h, const float* __restrict__ w,
                                  int K, int nchunk, float* __restrict__ partial) {
    const int r = blockIdx.y, cb = blockIdx.x;
    const int chunk = K / nchunk;
    const int j0 = cb * chunk;
    const int j1 = (cb == nchunk - 1) ? K : j0 + chunk;
    const float* wr = w + (size_t)r * K;
    float s = 0.f;
    for (int j = j0 + (int)threadIdx.x * 4; j + 3 < j1; j += blockDim.x * 4) {
        float4 hv = *reinterpret_cast<const float4*>(h + j);
        float4 wv = *reinterpret_cast<const float4*>(wr + j);
        s += hv.x * wv.x + hv.y * wv.y + hv.z * wv.z + hv.w * wv.w;
    }
    __shared__ float red[256];
    red[threadIdx.x] = s;
    __syncthreads();
    for (int off = 128; off > 0; off >>= 1) {
        if ((int)threadIdx.x < off) red[threadIdx.x] += red[threadIdx.x + off];
        __syncthreads();
    }
    if (threadIdx.x == 0) partial[r * gridDim.x + cb] = red[0];
}

__global__ void fc_final_kernel(const float* __restrict__ partial,
                                const float* __restrict__ b, int nchunk,
                                float* __restrict__ out) {
    int r = threadIdx.x;
    if (r < 50) {
        float s = b[r];
        for (int i = 0; i < nchunk; ++i) s += partial[r * nchunk + i];
        out[r] = s;
    }
}

// ---------------------------------------------------------------------------
extern "C" void kernel_launch(void* const* d_in, const int* in_sizes, int n_in,
                              void* d_out, int out_size, void* d_ws, size_t ws_size,
                              hipStream_t stream) {
    const float* x    = (const float*)d_in[0];
    const float* c1w  = (const float*)d_in[1];
    const float* c1b  = (const float*)d_in[2];
    const float* bn1g = (const float*)d_in[3];
    const float* bn1b = (const float*)d_in[4];
    const float* a1qw = (const float*)d_in[5];
    const float* a1qb = (const float*)d_in[6];
    const float* a1kw = (const float*)d_in[7];
    const float* a1kb = (const float*)d_in[8];
    const float* a1vw = (const float*)d_in[9];
    const float* a1vb = (const float*)d_in[10];
    const float* a1g  = (const float*)d_in[11];
    const float* c2w  = (const float*)d_in[12];
    const float* c2b  = (const float*)d_in[13];
    const float* bn2g = (const float*)d_in[14];
    const float* bn2b = (const float*)d_in[15];
    const float* a2qw = (const float*)d_in[16];
    const float* a2qb = (const float*)d_in[17];
    const float* a2kw = (const float*)d_in[18];
    const float* a2kb = (const float*)d_in[19];
    const float* a2vw = (const float*)d_in[20];
    const float* a2vb = (const float*)d_in[21];
    const float* a2g  = (const float*)d_in[22];
    const float* fcw  = (const float*)d_in[23];
    const float* fcb  = (const float*)d_in[24];
    float* out = (float*)d_out;

    const int N1 = 127 * 127;            // 16129
    const int N2 = 62 * 62;              // 3844
    const int NP1 = (N1 + 31) & ~31;     // 16160
    const int NP2 = (N2 + 31) & ~31;     // 3872
    const int NS1 = 8, NS2 = 16;
    const int CH1 = ((N1 + NS1 - 1) / NS1 + 31) & ~31;   // 2048
    const int CH2 = ((N2 + NS2 - 1) / NS2 + 31) & ~31;   // 256

    char* base = (char*)d_ws;
    size_t off = 0;
    auto alloc = [&](size_t bytes) {
        void* p = base + off;
        off += (bytes + 63) & ~(size_t)63;
        return p;
    };
    float* h1     = (float*)alloc(sizeof(float) * 32 * 254 * 254);
    float* bnSums = (float*)alloc(sizeof(float) * 256);   // [0..63] s1, [64..191] s2
    float* bnA    = (float*)alloc(sizeof(float) * 64);
    float* p1     = (float*)alloc(sizeof(float) * 32 * N1);
    float* q1     = (float*)alloc(sizeof(float) * 4 * NP1);
    float* k1     = (float*)alloc(sizeof(float) * 4 * NP1);
    unsigned short* v1 = (unsigned short*)alloc(sizeof(short) * 32 * NP1);
    float* l1     = (float*)alloc(sizeof(float) * NS1 * N1);
    float* a1p    = (float*)alloc(sizeof(float) * (size_t)NS1 * N1 * 32);
    float* ao1    = (float*)alloc(sizeof(float) * 32 * N1);
    float* h2     = (float*)alloc(sizeof(float) * 64 * 125 * 125);
    float* bnB    = (float*)alloc(sizeof(float) * 128);
    float* p2     = (float*)alloc(sizeof(float) * 64 * N2);
    float* q2     = (float*)alloc(sizeof(float) * 8 * NP2);
    float* k2     = (float*)alloc(sizeof(float) * 8 * NP2);
    unsigned short* v2 = (unsigned short*)alloc(sizeof(short) * 64 * NP2);
    float* l2     = (float*)alloc(sizeof(float) * NS2 * N2);
    float* a2p    = (float*)alloc(sizeof(float) * (size_t)NS2 * N2 * 64);
    float* ao2    = (float*)alloc(sizeof(float) * 64 * N2);
    float* fcp    = (float*)alloc(sizeof(float) * 2048);

    hipMemsetAsync(bnSums, 0, 256 * sizeof(float), stream);

    // ---- stage 1: conv1 [3,256,256] -> [32,254,254] (+BN sums)
    {
        size_t smem = (3 * 324 + 3 * 9 + 512) * sizeof(float);
        conv3x3_kernel<<<dim3(16, 16, 32), dim3(16, 16), smem, stream>>>(
            x, 3, 256, 256, c1w, c1b, h1, 254, 254, bnSums);
    }
    bn_final_kernel<<<1, 32, 0, stream>>>(bnSums, 32, 254 * 254, bn1g, bn1b, bnA);
    bn_pool_kernel<<<(32 * N1 + 255) / 256, 256, 0, stream>>>(
        h1, bnA, 254, 254, 127, 127, 32, p1);

    // ---- attention 1 (C=32, Cqk=4, N=16129)
    qkv_proj_kernel<<<dim3((N1 + 255) / 256, 5), 256, 0, stream>>>(
        p1, N1, NP1, 32, 4, a1qw, a1qb, a1kw, a1kb, a1vw, a1vb, q1, k1, v1);
    flash_mfma_kernel<4, 32><<<dim3((N1 + 63) / 64, NS1), 256, 0, stream>>>(
        q1, k1, v1, N1, NP1, CH1, l1, a1p);
    combine_kernel<<<dim3((N1 + 255) / 256, 2), 256, 0, stream>>>(
        a1p, l1, NS1, N1, 32, a1g, p1, ao1);

    // ---- stage 2: conv2 [32,127,127] -> [64,125,125] (+BN sums)
    {
        size_t smem = (32 * 324 + 32 * 9 + 512) * sizeof(float);
        conv3x3_kernel<<<dim3(8, 8, 64), dim3(16, 16), smem, stream>>>(
            ao1, 32, 127, 127, c2w, c2b, h2, 125, 125, bnSums + 64);
    }
    bn_final_kernel<<<1, 64, 0, stream>>>(bnSums + 64, 64, 125 * 125, bn2g, bn2b, bnB);
    bn_pool_kernel<<<(64 * N2 + 255) / 256, 256, 0, stream>>>(
        h2, bnB, 125, 125, 62, 62, 64, p2);

    // ---- attention 2 (C=64, Cqk=8, N=3844)
    qkv_proj_kernel<<<dim3((N2 + 255) / 256, 10), 256, 0, stream>>>(
        p2, N2, NP2, 64, 8, a2qw, a2qb, a2kw, a2kb, a2vw, a2vb, q2, k2, v2);
    flash_mfma_kernel<8, 64><<<dim3((N2 + 63) / 64, NS2), 256, 0, stream>>>(
        q2, k2, v2, N2, NP2, CH2, l2, a2p);
    combine_kernel<<<dim3((N2 + 255) / 256, 4), 256, 0, stream>>>(
        a2p, l2, NS2, N2, 64, a2g, p2, ao2);

    // ---- FC [246016] -> [50]
    fc_partial_kernel<<<dim3(32, 50), 256, 0, stream>>>(ao2, fcw, 64 * N2, 32, fcp);
    fc_final_kernel<<<1, 64, 0, stream>>>(fcp, fcb, 32, out);
}

// Round 4
// 455.056 us; speedup vs baseline: 1.3295x; 1.3295x over previous
//
#include <hip/hip_runtime.h>
#include <hip/hip_bf16.h>

typedef float f32x4 __attribute__((ext_vector_type(4)));
typedef short bf16x8 __attribute__((ext_vector_type(8)));

__device__ inline unsigned short f2bf(float x) {
    __hip_bfloat16 h = __float2bfloat16(x);
    return *reinterpret_cast<unsigned short*>(&h);
}

// ---------------------------------------------------------------------------
// 3x3 VALID conv, stride 1, fused BN-sum reduction (atomicAdd per channel).
// Block = 16x16 spatial tile, grid.z = oc. No early returns (barrier safety).
// ---------------------------------------------------------------------------
__global__ void conv3x3_kernel(const float* __restrict__ src, int Cin, int H, int W,
                               const float* __restrict__ w, const float* __restrict__ b,
                               float* __restrict__ dst, int OH, int OW,
                               float* __restrict__ bn_accum) {
    extern __shared__ float lds[];           // [Cin*324] x | [Cin*9] w | [512] red
    float* xs  = lds;
    float* ws  = lds + Cin * 324;
    float* red = ws + Cin * 9;
    const int oc  = blockIdx.z;
    const int tx0 = blockIdx.x * 16, ty0 = blockIdx.y * 16;
    const int tid = threadIdx.y * 16 + threadIdx.x;

    for (int i = tid; i < Cin * 9; i += 256) ws[i] = w[oc * Cin * 9 + i];
    {
        int ic = 0, rem = tid;               // tid < 256 < 324
        for (int i = tid; i < Cin * 324; i += 256) {
            int r  = rem / 18;
            int cc = rem - r * 18;
            int y = ty0 + r, x = tx0 + cc;
            xs[i] = (y < H && x < W) ? src[((size_t)ic * H + y) * W + x] : 0.f;
            rem += 256;
            if (rem >= 324) { rem -= 324; ++ic; }
        }
    }
    __syncthreads();

    const int ox = tx0 + threadIdx.x, oy = ty0 + threadIdx.y;
    const bool valid = (ox < OW && oy < OH);
    float acc = b[oc];
    for (int ic = 0; ic < Cin; ++ic) {
        const float* xp = &xs[ic * 324 + threadIdx.y * 18 + threadIdx.x];
        const float* wp = &ws[ic * 9];
        #pragma unroll
        for (int kh = 0; kh < 3; ++kh)
            #pragma unroll
            for (int kw = 0; kw < 3; ++kw)
                acc = fmaf(xp[kh * 18 + kw], wp[kh * 3 + kw], acc);
    }
    if (valid) dst[((size_t)oc * OH + oy) * OW + ox] = acc;

    // fused BN partial sums
    float vs = valid ? acc : 0.f;
    red[tid]       = vs;
    red[256 + tid] = vs * vs;
    __syncthreads();
    for (int off = 128; off > 0; off >>= 1) {
        if (tid < off) {
            red[tid]       += red[tid + off];
            red[256 + tid] += red[256 + tid + off];
        }
        __syncthreads();
    }
    if (tid == 0) {
        atomicAdd(&bn_accum[oc * 2],     red[0]);
        atomicAdd(&bn_accum[oc * 2 + 1], red[256]);
    }
}

// ---------------------------------------------------------------------------
// Finalize BN: sums -> (inv = g/sqrt(var+eps), shift = b - mean*inv).
// ---------------------------------------------------------------------------
__global__ void bn_final_kernel(const float* __restrict__ sums, int C, int spatial,
                                const float* __restrict__ g, const float* __restrict__ bb,
                                float* __restrict__ inv_shift) {
    int c = threadIdx.x;
    if (c >= C) return;
    float m   = sums[c * 2] / (float)spatial;
    float var = sums[c * 2 + 1] / (float)spatial - m * m;
    float inv = g[c] * rsqrtf(var + 1e-5f);
    inv_shift[c * 2]     = inv;
    inv_shift[c * 2 + 1] = bb[c] - m * inv;
}

// ---------------------------------------------------------------------------
// Fused BN-apply + ReLU + 2x2/2 max-pool (VALID).
// ---------------------------------------------------------------------------
__global__ void bn_pool_kernel(const float* __restrict__ src,
                               const float* __restrict__ inv_shift,
                               int H, int W, int OH, int OW, int C,
                               float* __restrict__ dst) {
    int i = blockIdx.x * blockDim.x + threadIdx.x;
    if (i >= C * OH * OW) return;
    int ox = i % OW;
    int oy = (i / OW) % OH;
    int c  = i / (OW * OH);
    float inv = inv_shift[c * 2], sh = inv_shift[c * 2 + 1];
    const float* p = src + ((size_t)c * H + 2 * oy) * W + 2 * ox;
    float a = fmaxf(fmaf(p[0],     inv, sh), 0.f);
    float b = fmaxf(fmaf(p[1],     inv, sh), 0.f);
    float d = fmaxf(fmaf(p[W],     inv, sh), 0.f);
    float e = fmaxf(fmaf(p[W + 1], inv, sh), 0.f);
    dst[i] = fmaxf(fmaxf(a, b), fmaxf(d, e));
}

// ---------------------------------------------------------------------------
// 1x1-conv QKV projection. q,k fp32 (stride NP); v bf16 (stride NP).
// ---------------------------------------------------------------------------
__global__ void qkv_proj_kernel(const float* __restrict__ xf, int N, int NP, int C, int Cqk,
                                const float* __restrict__ qw, const float* __restrict__ qb,
                                const float* __restrict__ kw, const float* __restrict__ kb,
                                const float* __restrict__ vw, const float* __restrict__ vb,
                                float* __restrict__ q, float* __restrict__ k,
                                unsigned short* __restrict__ v) {
    constexpr int OCG = 8;
    __shared__ float wl[OCG * 64 + OCG];
    const int g0 = blockIdx.y * OCG;
    const int tid = threadIdx.x;
    for (int i = tid; i < OCG * C; i += blockDim.x) {
        int o = i / C, cc = i % C;
        int oc = g0 + o;
        const float* wsrc = (oc < Cqk) ? (qw + oc * C)
                          : (oc < 2 * Cqk) ? (kw + (oc - Cqk) * C)
                          : (vw + (oc - 2 * Cqk) * C);
        wl[o * C + cc] = wsrc[cc];
    }
    if (tid < OCG) {
        int oc = g0 + tid;
        wl[OCG * C + tid] = (oc < Cqk) ? qb[oc]
                          : (oc < 2 * Cqk) ? kb[oc - Cqk]
                          : vb[oc - 2 * Cqk];
    }
    __syncthreads();
    int n = blockIdx.x * blockDim.x + tid;
    if (n >= N) return;
    float acc[OCG];
    #pragma unroll
    for (int o = 0; o < OCG; ++o) acc[o] = wl[OCG * C + o];
    for (int c = 0; c < C; ++c) {
        float xv = xf[(size_t)c * N + n];
        #pragma unroll
        for (int o = 0; o < OCG; ++o) acc[o] = fmaf(xv, wl[o * C + c], acc[o]);
    }
    #pragma unroll
    for (int o = 0; o < OCG; ++o) {
        int oc = g0 + o;
        if (oc < Cqk)            q[(size_t)oc * NP + n] = acc[o];
        else if (oc < 2 * Cqk)   k[(size_t)(oc - Cqk) * NP + n] = acc[o];
        else                     v[(size_t)(oc - 2 * Cqk) * NP + n] = f2bf(acc[o]);
    }
}

// ---------------------------------------------------------------------------
// MFMA flash attention v3: LDS-staged, 64-key chunks, conflict-free layout.
//   K in LDS [CQK][64] fp32 (reads are 16-lane broadcasts).
//   V in LDS [CV][72] bf16 (stride 72 shorts -> b128 reads are 2-way = free).
// Each lane: query = lane&15 (A-frag row / D col), key-octet = 8*(lane>>4).
// q pre-scaled by log2e -> p = exp2(e). Staging reads padded arrays (NP mult
// of 64) unmasked; out-of-range keys masked at p (only in last chunk of the
// final split). acc D-frag: ch = lane&15, query = qb + 4*(lane>>4) + reg.
// ---------------------------------------------------------------------------
template <int CQK, int CV>
__launch_bounds__(256)
__global__ void flash_mfma_kernel(const float* __restrict__ q,
                                  const float* __restrict__ k,
                                  const unsigned short* __restrict__ v,
                                  int N, int NP, int chunk,
                                  float* __restrict__ l_part,
                                  float* __restrict__ acc_part) {
    constexpr int VS = 72;                  // V LDS row stride (shorts)
    __shared__ float ksm[CQK * 64];
    __shared__ unsigned short vsm[CV * VS];
    const int tid  = threadIdx.x;
    const int wave = tid >> 6;
    const int lane = tid & 63;
    const int row  = lane & 15;
    const int g    = lane >> 4;
    const int s    = blockIdx.y;
    const int m0   = s * chunk;
    const int m1   = min(N, m0 + chunk);
    const int qb   = blockIdx.x * 64 + wave * 16;
    const int n    = qb + row;

    float qr[CQK];
    #pragma unroll
    for (int c = 0; c < CQK; ++c)
        qr[c] = (n < N) ? q[(size_t)c * NP + n] * 1.44269504f : 0.f;

    // staging coordinates (all threads participate)
    const int kc  = tid / 64,  kkk = tid % 64;         // K: element (c, kk)
    const int vch = tid / 8,   vkk = (tid % 8) * 8;    // V: ushort8 (ch, kk..kk+7)

    f32x4 acc[CV / 16];
    #pragma unroll
    for (int f = 0; f < CV / 16; ++f) acc[f] = (f32x4){0.f, 0.f, 0.f, 0.f};
    float lsum = 0.f;

    const int nchunks = (m1 - m0 + 63) >> 6;
    for (int t = 0; t < nchunks; ++t) {
        const int mt = m0 + t * 64;
        __syncthreads();                    // protect previous tile
        #pragma unroll
        for (int cc = 0; cc < CQK / 4; ++cc)   // CQK*64/256 elements per thread
            ksm[cc * 256 + tid] = k[(size_t)(kc + cc * 4) * NP + mt + kkk];
        #pragma unroll
        for (int vv = 0; vv < CV / 32; ++vv) { // CV*64/(256*8) ushort8 per thread
            int ch = vch + vv * 32;
            ushort4 a0 = *(const ushort4*)&v[(size_t)ch * NP + mt + vkk];
            ushort4 a1 = *(const ushort4*)&v[(size_t)ch * NP + mt + vkk + 4];
            *(ushort4*)&vsm[ch * VS + vkk]     = a0;
            *(ushort4*)&vsm[ch * VS + vkk + 4] = a1;
        }
        __syncthreads();

        const bool tail = (mt + 64 > m1);
        #pragma unroll
        for (int h = 0; h < 2; ++h) {
            const int kk0 = h * 32 + 8 * g;
            f32x4 e0 = (f32x4){0.f, 0.f, 0.f, 0.f};
            f32x4 e1 = (f32x4){0.f, 0.f, 0.f, 0.f};
            #pragma unroll
            for (int c = 0; c < CQK; ++c) {
                f32x4 ka = *(const f32x4*)&ksm[c * 64 + kk0];
                f32x4 kc2 = *(const f32x4*)&ksm[c * 64 + kk0 + 4];
                e0 += qr[c] * ka;
                e1 += qr[c] * kc2;
            }
            bf16x8 pfrag;
            if (!tail) {
                #pragma unroll
                for (int j = 0; j < 4; ++j) {
                    float p = exp2f(e0[j]); lsum += p; pfrag[j] = (short)f2bf(p);
                }
                #pragma unroll
                for (int j = 0; j < 4; ++j) {
                    float p = exp2f(e1[j]); lsum += p; pfrag[4 + j] = (short)f2bf(p);
                }
            } else {
                #pragma unroll
                for (int j = 0; j < 4; ++j) {
                    float p = (mt + kk0 + j < m1) ? exp2f(e0[j]) : 0.f;
                    lsum += p; pfrag[j] = (short)f2bf(p);
                }
                #pragma unroll
                for (int j = 0; j < 4; ++j) {
                    float p = (mt + kk0 + 4 + j < m1) ? exp2f(e1[j]) : 0.f;
                    lsum += p; pfrag[4 + j] = (short)f2bf(p);
                }
            }
            #pragma unroll
            for (int f = 0; f < CV / 16; ++f) {
                bf16x8 vf = *(const bf16x8*)&vsm[(f * 16 + row) * VS + kk0];
                acc[f] = __builtin_amdgcn_mfma_f32_16x16x32_bf16(pfrag, vf, acc[f], 0, 0, 0);
            }
        }
    }

    lsum += __shfl_xor(lsum, 16, 64);
    lsum += __shfl_xor(lsum, 32, 64);
    if (g == 0 && n < N) l_part[(size_t)s * N + n] = lsum;

    #pragma unroll
    for (int f = 0; f < CV / 16; ++f) {
        #pragma unroll
        for (int r2 = 0; r2 < 4; ++r2) {
            int nq = qb + 4 * g + r2;
            if (nq < N)
                acc_part[((size_t)s * N + nq) * CV + f * 16 + row] = acc[f][r2];
        }
    }
}

// ---------------------------------------------------------------------------
// Combine key-split partials. Thread-per-n, 16 cv channels per blockIdx.y.
// ---------------------------------------------------------------------------
__global__ void combine_kernel(const float* __restrict__ acc_part,
                               const float* __restrict__ l_part,
                               int nsplit, int N, int CV,
                               const float* __restrict__ gamma,
                               const float* __restrict__ x_res,
                               float* __restrict__ out) {
    int n = blockIdx.x * blockDim.x + threadIdx.x;
    if (n >= N) return;
    int cv0 = blockIdx.y * 16;
    float l = 0.f;
    for (int s = 0; s < nsplit; ++s) l += l_part[(size_t)s * N + n];
    f32x4 a[4];
    #pragma unroll
    for (int t = 0; t < 4; ++t) a[t] = (f32x4){0.f, 0.f, 0.f, 0.f};
    for (int s = 0; s < nsplit; ++s) {
        const float* p = acc_part + ((size_t)s * N + n) * CV + cv0;
        #pragma unroll
        for (int t = 0; t < 4; ++t) a[t] += *(const f32x4*)(p + 4 * t);
    }
    float gs = gamma[0] / l;
    #pragma unroll
    for (int t = 0; t < 4; ++t)
        #pragma unroll
        for (int u = 0; u < 4; ++u) {
            int cv = cv0 + 4 * t + u;
            out[(size_t)cv * N + n] = fmaf(gs, a[t][u], x_res[(size_t)cv * N + n]);
        }
}

// ---------------------------------------------------------------------------
// FC: out[50] = h @ W^T + b.
// ---------------------------------------------------------------------------
__global__ void fc_partial_kernel(const float* __restrict__ h, const float* __restrict__ w,
                                  int K, int nchunk, float* __restrict__ partial) {
    const int r = blockIdx.y, cb = blockIdx.x;
    const int chunk = K / nchunk;
    const int j0 = cb * chunk;
    const int j1 = (cb == nchunk - 1) ? K : j0 + chunk;
    const float* wr = w + (size_t)r * K;
    float s = 0.f;
    for (int j = j0 + (int)threadIdx.x * 4; j + 3 < j1; j += blockDim.x * 4) {
        float4 hv = *reinterpret_cast<const float4*>(h + j);
        float4 wv = *reinterpret_cast<const float4*>(wr + j);
        s += hv.x * wv.x + hv.y * wv.y + hv.z * wv.z + hv.w * wv.w;
    }
    __shared__ float red[256];
    red[threadIdx.x] = s;
    __syncthreads();
    for (int off = 128; off > 0; off >>= 1) {
        if ((int)threadIdx.x < off) red[threadIdx.x] += red[threadIdx.x + off];
        __syncthreads();
    }
    if (threadIdx.x == 0) partial[r * gridDim.x + cb] = red[0];
}

__global__ void fc_final_kernel(const float* __restrict__ partial,
                                const float* __restrict__ b, int nchunk,
                                float* __restrict__ out) {
    int r = threadIdx.x;
    if (r < 50) {
        float s = b[r];
        for (int i = 0; i < nchunk; ++i) s += partial[r * nchunk + i];
        out[r] = s;
    }
}

// ---------------------------------------------------------------------------
extern "C" void kernel_launch(void* const* d_in, const int* in_sizes, int n_in,
                              void* d_out, int out_size, void* d_ws, size_t ws_size,
                              hipStream_t stream) {
    const float* x    = (const float*)d_in[0];
    const float* c1w  = (const float*)d_in[1];
    const float* c1b  = (const float*)d_in[2];
    const float* bn1g = (const float*)d_in[3];
    const float* bn1b = (const float*)d_in[4];
    const float* a1qw = (const float*)d_in[5];
    const float* a1qb = (const float*)d_in[6];
    const float* a1kw = (const float*)d_in[7];
    const float* a1kb = (const float*)d_in[8];
    const float* a1vw = (const float*)d_in[9];
    const float* a1vb = (const float*)d_in[10];
    const float* a1g  = (const float*)d_in[11];
    const float* c2w  = (const float*)d_in[12];
    const float* c2b  = (const float*)d_in[13];
    const float* bn2g = (const float*)d_in[14];
    const float* bn2b = (const float*)d_in[15];
    const float* a2qw = (const float*)d_in[16];
    const float* a2qb = (const float*)d_in[17];
    const float* a2kw = (const float*)d_in[18];
    const float* a2kb = (const float*)d_in[19];
    const float* a2vw = (const float*)d_in[20];
    const float* a2vb = (const float*)d_in[21];
    const float* a2g  = (const float*)d_in[22];
    const float* fcw  = (const float*)d_in[23];
    const float* fcb  = (const float*)d_in[24];
    float* out = (float*)d_out;

    const int N1 = 127 * 127;            // 16129
    const int N2 = 62 * 62;              // 3844
    const int NP1 = (N1 + 63) & ~63;     // 16192
    const int NP2 = (N2 + 63) & ~63;     // 3904
    const int NS1 = 8, NS2 = 16;
    const int CH1 = 2048;                // ceil(N1/NS1) -> 64-aligned
    const int CH2 = 256;                 // ceil(N2/NS2) -> 64-aligned

    char* base = (char*)d_ws;
    size_t off = 0;
    auto alloc = [&](size_t bytes) {
        void* p = base + off;
        off += (bytes + 63) & ~(size_t)63;
        return p;
    };
    float* h1     = (float*)alloc(sizeof(float) * 32 * 254 * 254);
    float* bnSums = (float*)alloc(sizeof(float) * 256);
    float* bnA    = (float*)alloc(sizeof(float) * 64);
    float* p1     = (float*)alloc(sizeof(float) * 32 * N1);
    float* q1     = (float*)alloc(sizeof(float) * 4 * NP1);
    float* k1     = (float*)alloc(sizeof(float) * 4 * NP1);
    unsigned short* v1 = (unsigned short*)alloc(sizeof(short) * 32 * NP1);
    float* l1     = (float*)alloc(sizeof(float) * NS1 * N1);
    float* a1p    = (float*)alloc(sizeof(float) * (size_t)NS1 * N1 * 32);
    float* ao1    = (float*)alloc(sizeof(float) * 32 * N1);
    float* h2     = (float*)alloc(sizeof(float) * 64 * 125 * 125);
    float* bnB    = (float*)alloc(sizeof(float) * 128);
    float* p2     = (float*)alloc(sizeof(float) * 64 * N2);
    float* q2     = (float*)alloc(sizeof(float) * 8 * NP2);
    float* k2     = (float*)alloc(sizeof(float) * 8 * NP2);
    unsigned short* v2 = (unsigned short*)alloc(sizeof(short) * 64 * NP2);
    float* l2     = (float*)alloc(sizeof(float) * NS2 * N2);
    float* a2p    = (float*)alloc(sizeof(float) * (size_t)NS2 * N2 * 64);
    float* ao2    = (float*)alloc(sizeof(float) * 64 * N2);
    float* fcp    = (float*)alloc(sizeof(float) * 2048);

    hipMemsetAsync(bnSums, 0, 256 * sizeof(float), stream);

    // ---- stage 1: conv1 [3,256,256] -> [32,254,254] (+BN sums)
    {
        size_t smem = (3 * 324 + 3 * 9 + 512) * sizeof(float);
        conv3x3_kernel<<<dim3(16, 16, 32), dim3(16, 16), smem, stream>>>(
            x, 3, 256, 256, c1w, c1b, h1, 254, 254, bnSums);
    }
    bn_final_kernel<<<1, 32, 0, stream>>>(bnSums, 32, 254 * 254, bn1g, bn1b, bnA);
    bn_pool_kernel<<<(32 * N1 + 255) / 256, 256, 0, stream>>>(
        h1, bnA, 254, 254, 127, 127, 32, p1);

    // ---- attention 1 (C=32, Cqk=4, N=16129)
    qkv_proj_kernel<<<dim3((N1 + 255) / 256, 5), 256, 0, stream>>>(
        p1, N1, NP1, 32, 4, a1qw, a1qb, a1kw, a1kb, a1vw, a1vb, q1, k1, v1);
    flash_mfma_kernel<4, 32><<<dim3((N1 + 63) / 64, NS1), 256, 0, stream>>>(
        q1, k1, v1, N1, NP1, CH1, l1, a1p);
    combine_kernel<<<dim3((N1 + 255) / 256, 2), 256, 0, stream>>>(
        a1p, l1, NS1, N1, 32, a1g, p1, ao1);

    // ---- stage 2: conv2 [32,127,127] -> [64,125,125] (+BN sums)
    {
        size_t smem = (32 * 324 + 32 * 9 + 512) * sizeof(float);
        conv3x3_kernel<<<dim3(8, 8, 64), dim3(16, 16), smem, stream>>>(
            ao1, 32, 127, 127, c2w, c2b, h2, 125, 125, bnSums + 64);
    }
    bn_final_kernel<<<1, 64, 0, stream>>>(bnSums + 64, 64, 125 * 125, bn2g, bn2b, bnB);
    bn_pool_kernel<<<(64 * N2 + 255) / 256, 256, 0, stream>>>(
        h2, bnB, 125, 125, 62, 62, 64, p2);

    // ---- attention 2 (C=64, Cqk=8, N=3844)
    qkv_proj_kernel<<<dim3((N2 + 255) / 256, 10), 256, 0, stream>>>(
        p2, N2, NP2, 64, 8, a2qw, a2qb, a2kw, a2kb, a2vw, a2vb, q2, k2, v2);
    flash_mfma_kernel<8, 64><<<dim3((N2 + 63) / 64, NS2), 256, 0, stream>>>(
        q2, k2, v2, N2, NP2, CH2, l2, a2p);
    combine_kernel<<<dim3((N2 + 255) / 256, 4), 256, 0, stream>>>(
        a2p, l2, NS2, N2, 64, a2g, p2, ao2);

    // ---- FC [246016] -> [50]
    fc_partial_kernel<<<dim3(32, 50), 256, 0, stream>>>(ao2, fcw, 64 * N2, 32, fcp);
    fc_final_kernel<<<1, 64, 0, stream>>>(fcp, fcb, 32, out);
}

// Round 5
// 311.046 us; speedup vs baseline: 1.9450x; 1.4630x over previous
//
#include <hip/hip_runtime.h>
#include <hip/hip_bf16.h>

typedef float f32x4 __attribute__((ext_vector_type(4)));
typedef short bf16x8 __attribute__((ext_vector_type(8)));

__device__ inline unsigned short f2bf(float x) {
    __hip_bfloat16 h = __float2bfloat16(x);
    return *reinterpret_cast<unsigned short*>(&h);
}

// ---------------------------------------------------------------------------
// Register-tiled 3x3 VALID conv (stride 1) + fused BN-sum reduction.
// Block = 256 threads; each thread computes a 1x4 output strip -> the block
// covers a 16-high x 64-wide output tile. grid = (ceil(OW/64), ceil(OH/16), OC).
// Input staged in LDS per ICB-channel group: [ICB][18][68] (68 = 64+2 used +2
// pad so &xs[c][r][4k] is 16B-aligned -> ds_read_b128). Weights padded [ICB][12]
// -> 2x b128 + b32 broadcast reads. Per ic: 9 LDS reads feed 36 FMA.
// No early returns (barrier safety); OOB outputs masked at store/BN-sum.
// ---------------------------------------------------------------------------
template <int CIN, int ICB>
__launch_bounds__(256)
__global__ void conv3x3_rt_kernel(const float* __restrict__ src, int H, int W,
                                  const float* __restrict__ w,
                                  const float* __restrict__ b,
                                  float* __restrict__ dst, int OH, int OW,
                                  float* __restrict__ bn_accum) {
    __shared__ __align__(16) float xs[ICB][18][68];
    __shared__ __align__(16) float wsm[ICB][12];
    __shared__ float red[512];

    const int oc  = blockIdx.z;
    const int ox0 = blockIdx.x * 64;
    const int oy0 = blockIdx.y * 16;
    const int tid = threadIdx.x;
    const int ty  = tid >> 4;
    const int tx  = (tid & 15) << 2;

    float o0, o1, o2, o3;
    o0 = o1 = o2 = o3 = b[oc];

    // staging coords: wave-uniform slot (tid>>6), 64-wide coalesced rows
    const int scol   = tid & 63;
    const int sslot0 = tid >> 6;
    const bool colok = (ox0 + scol) < W;

    for (int icb = 0; icb < CIN; icb += ICB) {
        __syncthreads();                     // protect previous tile
        // body: cols 0..63 of each (c,r) row; slot s = c*18 + r, step 4
        {
            int s  = sslot0;
            int rr = sslot0;                 // c = 0 initially (sslot0 < 18)
            const float* gp = src + ((size_t)icb * H + oy0 + rr) * W + ox0 + scol;
            float* lp = &xs[0][0][0] + (size_t)s * 68 + scol;
            while (s < ICB * 18) {
                int y = oy0 + rr;
                *lp = (y < H && colok) ? *gp : 0.f;
                s += 4; rr += 4;
                gp += 4 * (size_t)W;
                lp += 4 * 68;
                if (rr >= 18) { rr -= 18; gp += ((size_t)H - 18) * W; }
            }
        }
        // fringe: cols 64,65
        if (tid < ICB * 18) {
            int c = tid / 18, r = tid - c * 18;
            int y = oy0 + r;
            const float* gp = src + ((size_t)(icb + c) * H + y) * W + ox0 + 64;
            bool yok = (y < H);
            xs[c][r][64] = (yok && (ox0 + 64) < W) ? gp[0] : 0.f;
            xs[c][r][65] = (yok && (ox0 + 65) < W) ? gp[1] : 0.f;
        }
        // weights (12-padded rows)
        if (tid < ICB * 9) {
            int c = tid / 9, j = tid - c * 9;
            wsm[c][j] = w[((size_t)oc * CIN + icb + c) * 9 + j];
        }
        __syncthreads();

        #pragma unroll
        for (int c = 0; c < ICB; ++c) {
            float wv[9];
            #pragma unroll
            for (int j = 0; j < 9; ++j) wv[j] = wsm[c][j];
            #pragma unroll
            for (int kh = 0; kh < 3; ++kh) {
                const float* xp = &xs[c][ty + kh][tx];
                f32x4 x03 = *(const f32x4*)xp;       // ds_read_b128
                float x4 = xp[4], x5 = xp[5];        // ds_read_b64
                const float w0 = wv[kh * 3], w1 = wv[kh * 3 + 1], w2 = wv[kh * 3 + 2];
                o0 = fmaf(x03[0], w0, o0); o0 = fmaf(x03[1], w1, o0); o0 = fmaf(x03[2], w2, o0);
                o1 = fmaf(x03[1], w0, o1); o1 = fmaf(x03[2], w1, o1); o1 = fmaf(x03[3], w2, o1);
                o2 = fmaf(x03[2], w0, o2); o2 = fmaf(x03[3], w1, o2); o2 = fmaf(x4,     w2, o2);
                o3 = fmaf(x03[3], w0, o3); o3 = fmaf(x4,     w1, o3); o3 = fmaf(x5,     w2, o3);
            }
        }
    }

    // store + BN partial sums
    const int oy = oy0 + ty;
    const int ox = ox0 + tx;
    float s1 = 0.f, s2 = 0.f;
    if (oy < OH) {
        float* dp = dst + ((size_t)oc * OH + oy) * OW + ox;
        if (ox + 0 < OW) { dp[0] = o0; s1 += o0; s2 = fmaf(o0, o0, s2); }
        if (ox + 1 < OW) { dp[1] = o1; s1 += o1; s2 = fmaf(o1, o1, s2); }
        if (ox + 2 < OW) { dp[2] = o2; s1 += o2; s2 = fmaf(o2, o2, s2); }
        if (ox + 3 < OW) { dp[3] = o3; s1 += o3; s2 = fmaf(o3, o3, s2); }
    }
    red[tid]       = s1;
    red[256 + tid] = s2;
    __syncthreads();
    for (int off2 = 128; off2 > 0; off2 >>= 1) {
        if (tid < off2) {
            red[tid]       += red[tid + off2];
            red[256 + tid] += red[256 + tid + off2];
        }
        __syncthreads();
    }
    if (tid == 0) {
        atomicAdd(&bn_accum[oc * 2],     red[0]);
        atomicAdd(&bn_accum[oc * 2 + 1], red[256]);
    }
}

// ---------------------------------------------------------------------------
// Finalize BN: sums -> (inv = g/sqrt(var+eps), shift = b - mean*inv).
// ---------------------------------------------------------------------------
__global__ void bn_final_kernel(const float* __restrict__ sums, int C, int spatial,
                                const float* __restrict__ g, const float* __restrict__ bb,
                                float* __restrict__ inv_shift) {
    int c = threadIdx.x;
    if (c >= C) return;
    float m   = sums[c * 2] / (float)spatial;
    float var = sums[c * 2 + 1] / (float)spatial - m * m;
    float inv = g[c] * rsqrtf(var + 1e-5f);
    inv_shift[c * 2]     = inv;
    inv_shift[c * 2 + 1] = bb[c] - m * inv;
}

// ---------------------------------------------------------------------------
// Fused BN-apply + ReLU + 2x2/2 max-pool (VALID).
// ---------------------------------------------------------------------------
__global__ void bn_pool_kernel(const float* __restrict__ src,
                               const float* __restrict__ inv_shift,
                               int H, int W, int OH, int OW, int C,
                               float* __restrict__ dst) {
    int i = blockIdx.x * blockDim.x + threadIdx.x;
    if (i >= C * OH * OW) return;
    int ox = i % OW;
    int oy = (i / OW) % OH;
    int c  = i / (OW * OH);
    float inv = inv_shift[c * 2], sh = inv_shift[c * 2 + 1];
    const float* p = src + ((size_t)c * H + 2 * oy) * W + 2 * ox;
    float a = fmaxf(fmaf(p[0],     inv, sh), 0.f);
    float b = fmaxf(fmaf(p[1],     inv, sh), 0.f);
    float d = fmaxf(fmaf(p[W],     inv, sh), 0.f);
    float e = fmaxf(fmaf(p[W + 1], inv, sh), 0.f);
    dst[i] = fmaxf(fmaxf(a, b), fmaxf(d, e));
}

// ---------------------------------------------------------------------------
// 1x1-conv QKV projection. q,k fp32 (stride NP); v bf16 (stride NP).
// ---------------------------------------------------------------------------
__global__ void qkv_proj_kernel(const float* __restrict__ xf, int N, int NP, int C, int Cqk,
                                const float* __restrict__ qw, const float* __restrict__ qb,
                                const float* __restrict__ kw, const float* __restrict__ kb,
                                const float* __restrict__ vw, const float* __restrict__ vb,
                                float* __restrict__ q, float* __restrict__ k,
                                unsigned short* __restrict__ v) {
    constexpr int OCG = 8;
    __shared__ float wl[OCG * 64 + OCG];
    const int g0 = blockIdx.y * OCG;
    const int tid = threadIdx.x;
    for (int i = tid; i < OCG * C; i += blockDim.x) {
        int o = i / C, cc = i % C;
        int oc = g0 + o;
        const float* wsrc = (oc < Cqk) ? (qw + oc * C)
                          : (oc < 2 * Cqk) ? (kw + (oc - Cqk) * C)
                          : (vw + (oc - 2 * Cqk) * C);
        wl[o * C + cc] = wsrc[cc];
    }
    if (tid < OCG) {
        int oc = g0 + tid;
        wl[OCG * C + tid] = (oc < Cqk) ? qb[oc]
                          : (oc < 2 * Cqk) ? kb[oc - Cqk]
                          : vb[oc - 2 * Cqk];
    }
    __syncthreads();
    int n = blockIdx.x * blockDim.x + tid;
    if (n >= N) return;
    float acc[OCG];
    #pragma unroll
    for (int o = 0; o < OCG; ++o) acc[o] = wl[OCG * C + o];
    for (int c = 0; c < C; ++c) {
        float xv = xf[(size_t)c * N + n];
        #pragma unroll
        for (int o = 0; o < OCG; ++o) acc[o] = fmaf(xv, wl[o * C + c], acc[o]);
    }
    #pragma unroll
    for (int o = 0; o < OCG; ++o) {
        int oc = g0 + o;
        if (oc < Cqk)            q[(size_t)oc * NP + n] = acc[o];
        else if (oc < 2 * Cqk)   k[(size_t)(oc - Cqk) * NP + n] = acc[o];
        else                     v[(size_t)(oc - 2 * Cqk) * NP + n] = f2bf(acc[o]);
    }
}

// ---------------------------------------------------------------------------
// MFMA flash attention: LDS-staged, 64-key chunks, conflict-free layout.
//   K in LDS [CQK][64] fp32 (reads are 16-lane broadcasts).
//   V in LDS [CV][72] bf16 (stride 72 shorts -> b128 reads are 2-way = free).
// Each lane: query = lane&15 (A-frag row / D col), key-octet = 8*(lane>>4).
// q pre-scaled by log2e -> p = exp2(e). Staging reads padded arrays (NP mult
// of 64) unmasked; out-of-range keys masked at p (only in last chunk of the
// final split). acc D-frag: ch = lane&15, query = qb + 4*(lane>>4) + reg.
// ---------------------------------------------------------------------------
template <int CQK, int CV>
__launch_bounds__(256)
__global__ void flash_mfma_kernel(const float* __restrict__ q,
                                  const float* __restrict__ k,
                                  const unsigned short* __restrict__ v,
                                  int N, int NP, int chunk,
                                  float* __restrict__ l_part,
                                  float* __restrict__ acc_part) {
    constexpr int VS = 72;                  // V LDS row stride (shorts)
    __shared__ float ksm[CQK * 64];
    __shared__ unsigned short vsm[CV * VS];
    const int tid  = threadIdx.x;
    const int wave = tid >> 6;
    const int lane = tid & 63;
    const int row  = lane & 15;
    const int g    = lane >> 4;
    const int s    = blockIdx.y;
    const int m0   = s * chunk;
    const int m1   = min(N, m0 + chunk);
    const int qb   = blockIdx.x * 64 + wave * 16;
    const int n    = qb + row;

    float qr[CQK];
    #pragma unroll
    for (int c = 0; c < CQK; ++c)
        qr[c] = (n < N) ? q[(size_t)c * NP + n] * 1.44269504f : 0.f;

    // staging coordinates (all threads participate)
    const int kc  = tid / 64,  kkk = tid % 64;         // K: element (c, kk)
    const int vch = tid / 8,   vkk = (tid % 8) * 8;    // V: ushort8 (ch, kk..kk+7)

    f32x4 acc[CV / 16];
    #pragma unroll
    for (int f = 0; f < CV / 16; ++f) acc[f] = (f32x4){0.f, 0.f, 0.f, 0.f};
    float lsum = 0.f;

    const int nchunks = (m1 - m0 + 63) >> 6;
    for (int t = 0; t < nchunks; ++t) {
        const int mt = m0 + t * 64;
        __syncthreads();                    // protect previous tile
        #pragma unroll
        for (int cc = 0; cc < CQK / 4; ++cc)   // CQK*64/256 elements per thread
            ksm[cc * 256 + tid] = k[(size_t)(kc + cc * 4) * NP + mt + kkk];
        #pragma unroll
        for (int vv = 0; vv < CV / 32; ++vv) { // CV*64/(256*8) ushort8 per thread
            int ch = vch + vv * 32;
            ushort4 a0 = *(const ushort4*)&v[(size_t)ch * NP + mt + vkk];
            ushort4 a1 = *(const ushort4*)&v[(size_t)ch * NP + mt + vkk + 4];
            *(ushort4*)&vsm[ch * VS + vkk]     = a0;
            *(ushort4*)&vsm[ch * VS + vkk + 4] = a1;
        }
        __syncthreads();

        const bool tail = (mt + 64 > m1);
        #pragma unroll
        for (int h = 0; h < 2; ++h) {
            const int kk0 = h * 32 + 8 * g;
            f32x4 e0 = (f32x4){0.f, 0.f, 0.f, 0.f};
            f32x4 e1 = (f32x4){0.f, 0.f, 0.f, 0.f};
            #pragma unroll
            for (int c = 0; c < CQK; ++c) {
                f32x4 ka  = *(const f32x4*)&ksm[c * 64 + kk0];
                f32x4 kc2 = *(const f32x4*)&ksm[c * 64 + kk0 + 4];
                e0 += qr[c] * ka;
                e1 += qr[c] * kc2;
            }
            bf16x8 pfrag;
            if (!tail) {
                #pragma unroll
                for (int j = 0; j < 4; ++j) {
                    float p = exp2f(e0[j]); lsum += p; pfrag[j] = (short)f2bf(p);
                }
                #pragma unroll
                for (int j = 0; j < 4; ++j) {
                    float p = exp2f(e1[j]); lsum += p; pfrag[4 + j] = (short)f2bf(p);
                }
            } else {
                #pragma unroll
                for (int j = 0; j < 4; ++j) {
                    float p = (mt + kk0 + j < m1) ? exp2f(e0[j]) : 0.f;
                    lsum += p; pfrag[j] = (short)f2bf(p);
                }
                #pragma unroll
                for (int j = 0; j < 4; ++j) {
                    float p = (mt + kk0 + 4 + j < m1) ? exp2f(e1[j]) : 0.f;
                    lsum += p; pfrag[4 + j] = (short)f2bf(p);
                }
            }
            #pragma unroll
            for (int f = 0; f < CV / 16; ++f) {
                bf16x8 vf = *(const bf16x8*)&vsm[(f * 16 + row) * VS + kk0];
                acc[f] = __builtin_amdgcn_mfma_f32_16x16x32_bf16(pfrag, vf, acc[f], 0, 0, 0);
            }
        }
    }

    lsum += __shfl_xor(lsum, 16, 64);
    lsum += __shfl_xor(lsum, 32, 64);
    if (g == 0 && n < N) l_part[(size_t)s * N + n] = lsum;

    #pragma unroll
    for (int f = 0; f < CV / 16; ++f) {
        #pragma unroll
        for (int r2 = 0; r2 < 4; ++r2) {
            int nq = qb + 4 * g + r2;
            if (nq < N)
                acc_part[((size_t)s * N + nq) * CV + f * 16 + row] = acc[f][r2];
        }
    }
}

// ---------------------------------------------------------------------------
// Combine key-split partials. Thread-per-n, 16 cv channels per blockIdx.y.
// ---------------------------------------------------------------------------
__global__ void combine_kernel(const float* __restrict__ acc_part,
                               const float* __restrict__ l_part,
                               int nsplit, int N, int CV,
                               const float* __restrict__ gamma,
                               const float* __restrict__ x_res,
                               float* __restrict__ out) {
    int n = blockIdx.x * blockDim.x + threadIdx.x;
    if (n >= N) return;
    int cv0 = blockIdx.y * 16;
    float l = 0.f;
    for (int s = 0; s < nsplit; ++s) l += l_part[(size_t)s * N + n];
    f32x4 a[4];
    #pragma unroll
    for (int t = 0; t < 4; ++t) a[t] = (f32x4){0.f, 0.f, 0.f, 0.f};
    for (int s = 0; s < nsplit; ++s) {
        const float* p = acc_part + ((size_t)s * N + n) * CV + cv0;
        #pragma unroll
        for (int t = 0; t < 4; ++t) a[t] += *(const f32x4*)(p + 4 * t);
    }
    float gs = gamma[0] / l;
    #pragma unroll
    for (int t = 0; t < 4; ++t)
        #pragma unroll
        for (int u = 0; u < 4; ++u) {
            int cv = cv0 + 4 * t + u;
            out[(size_t)cv * N + n] = fmaf(gs, a[t][u], x_res[(size_t)cv * N + n]);
        }
}

// ---------------------------------------------------------------------------
// FC: out[50] = h @ W^T + b.
// ---------------------------------------------------------------------------
__global__ void fc_partial_kernel(const float* __restrict__ h, const float* __restrict__ w,
                                  int K, int nchunk, float* __restrict__ partial) {
    const int r = blockIdx.y, cb = blockIdx.x;
    const int chunk = K / nchunk;
    const int j0 = cb * chunk;
    const int j1 = (cb == nchunk - 1) ? K : j0 + chunk;
    const float* wr = w + (size_t)r * K;
    float s = 0.f;
    for (int j = j0 + (int)threadIdx.x * 4; j + 3 < j1; j += blockDim.x * 4) {
        float4 hv = *reinterpret_cast<const float4*>(h + j);
        float4 wv = *reinterpret_cast<const float4*>(wr + j);
        s += hv.x * wv.x + hv.y * wv.y + hv.z * wv.z + hv.w * wv.w;
    }
    __shared__ float red[256];
    red[threadIdx.x] = s;
    __syncthreads();
    for (int off = 128; off > 0; off >>= 1) {
        if ((int)threadIdx.x < off) red[threadIdx.x] += red[threadIdx.x + off];
        __syncthreads();
    }
    if (threadIdx.x == 0) partial[r * gridDim.x + cb] = red[0];
}

__global__ void fc_final_kernel(const float* __restrict__ partial,
                                const float* __restrict__ b, int nchunk,
                                float* __restrict__ out) {
    int r = threadIdx.x;
    if (r < 50) {
        float s = b[r];
        for (int i = 0; i < nchunk; ++i) s += partial[r * nchunk + i];
        out[r] = s;
    }
}

// ---------------------------------------------------------------------------
extern "C" void kernel_launch(void* const* d_in, const int* in_sizes, int n_in,
                              void* d_out, int out_size, void* d_ws, size_t ws_size,
                              hipStream_t stream) {
    const float* x    = (const float*)d_in[0];
    const float* c1w  = (const float*)d_in[1];
    const float* c1b  = (const float*)d_in[2];
    const float* bn1g = (const float*)d_in[3];
    const float* bn1b = (const float*)d_in[4];
    const float* a1qw = (const float*)d_in[5];
    const float* a1qb = (const float*)d_in[6];
    const float* a1kw = (const float*)d_in[7];
    const float* a1kb = (const float*)d_in[8];
    const float* a1vw = (const float*)d_in[9];
    const float* a1vb = (const float*)d_in[10];
    const float* a1g  = (const float*)d_in[11];
    const float* c2w  = (const float*)d_in[12];
    const float* c2b  = (const float*)d_in[13];
    const float* bn2g = (const float*)d_in[14];
    const float* bn2b = (const float*)d_in[15];
    const float* a2qw = (const float*)d_in[16];
    const float* a2qb = (const float*)d_in[17];
    const float* a2kw = (const float*)d_in[18];
    const float* a2kb = (const float*)d_in[19];
    const float* a2vw = (const float*)d_in[20];
    const float* a2vb = (const float*)d_in[21];
    const float* a2g  = (const float*)d_in[22];
    const float* fcw  = (const float*)d_in[23];
    const float* fcb  = (const float*)d_in[24];
    float* out = (float*)d_out;

    const int N1 = 127 * 127;            // 16129
    const int N2 = 62 * 62;              // 3844
    const int NP1 = (N1 + 63) & ~63;     // 16192
    const int NP2 = (N2 + 63) & ~63;     // 3904
    const int NS1 = 8, NS2 = 16;
    const int CH1 = 2048;                // ceil(N1/NS1) -> 64-aligned
    const int CH2 = 256;                 // ceil(N2/NS2) -> 64-aligned

    char* base = (char*)d_ws;
    size_t off = 0;
    auto alloc = [&](size_t bytes) {
        void* p = base + off;
        off += (bytes + 63) & ~(size_t)63;
        return p;
    };
    float* h1     = (float*)alloc(sizeof(float) * 32 * 254 * 254);
    float* bnSums = (float*)alloc(sizeof(float) * 256);
    float* bnA    = (float*)alloc(sizeof(float) * 64);
    float* p1     = (float*)alloc(sizeof(float) * 32 * N1);
    float* q1     = (float*)alloc(sizeof(float) * 4 * NP1);
    float* k1     = (float*)alloc(sizeof(float) * 4 * NP1);
    unsigned short* v1 = (unsigned short*)alloc(sizeof(short) * 32 * NP1);
    float* l1     = (float*)alloc(sizeof(float) * NS1 * N1);
    float* a1p    = (float*)alloc(sizeof(float) * (size_t)NS1 * N1 * 32);
    float* ao1    = (float*)alloc(sizeof(float) * 32 * N1);
    float* h2     = (float*)alloc(sizeof(float) * 64 * 125 * 125);
    float* bnB    = (float*)alloc(sizeof(float) * 128);
    float* p2     = (float*)alloc(sizeof(float) * 64 * N2);
    float* q2     = (float*)alloc(sizeof(float) * 8 * NP2);
    float* k2     = (float*)alloc(sizeof(float) * 8 * NP2);
    unsigned short* v2 = (unsigned short*)alloc(sizeof(short) * 64 * NP2);
    float* l2     = (float*)alloc(sizeof(float) * NS2 * N2);
    float* a2p    = (float*)alloc(sizeof(float) * (size_t)NS2 * N2 * 64);
    float* ao2    = (float*)alloc(sizeof(float) * 64 * N2);
    float* fcp    = (float*)alloc(sizeof(float) * 2048);

    hipMemsetAsync(bnSums, 0, 256 * sizeof(float), stream);

    // ---- stage 1: conv1 [3,256,256] -> [32,254,254] (+BN sums)
    conv3x3_rt_kernel<3, 3><<<dim3(4, 16, 32), 256, 0, stream>>>(
        x, 256, 256, c1w, c1b, h1, 254, 254, bnSums);
    bn_final_kernel<<<1, 32, 0, stream>>>(bnSums, 32, 254 * 254, bn1g, bn1b, bnA);
    bn_pool_kernel<<<(32 * N1 + 255) / 256, 256, 0, stream>>>(
        h1, bnA, 254, 254, 127, 127, 32, p1);

    // ---- attention 1 (C=32, Cqk=4, N=16129)
    qkv_proj_kernel<<<dim3((N1 + 255) / 256, 5), 256, 0, stream>>>(
        p1, N1, NP1, 32, 4, a1qw, a1qb, a1kw, a1kb, a1vw, a1vb, q1, k1, v1);
    flash_mfma_kernel<4, 32><<<dim3((N1 + 63) / 64, NS1), 256, 0, stream>>>(
        q1, k1, v1, N1, NP1, CH1, l1, a1p);
    combine_kernel<<<dim3((N1 + 255) / 256, 2), 256, 0, stream>>>(
        a1p, l1, NS1, N1, 32, a1g, p1, ao1);

    // ---- stage 2: conv2 [32,127,127] -> [64,125,125] (+BN sums)
    conv3x3_rt_kernel<32, 8><<<dim3(2, 8, 64), 256, 0, stream>>>(
        ao1, 127, 127, c2w, c2b, h2, 125, 125, bnSums + 64);
    bn_final_kernel<<<1, 64, 0, stream>>>(bnSums + 64, 64, 125 * 125, bn2g, bn2b, bnB);
    bn_pool_kernel<<<(64 * N2 + 255) / 256, 256, 0, stream>>>(
        h2, bnB, 125, 125, 62, 62, 64, p2);

    // ---- attention 2 (C=64, Cqk=8, N=3844)
    qkv_proj_kernel<<<dim3((N2 + 255) / 256, 10), 256, 0, stream>>>(
        p2, N2, NP2, 64, 8, a2qw, a2qb, a2kw, a2kb, a2vw, a2vb, q2, k2, v2);
    flash_mfma_kernel<8, 64><<<dim3((N2 + 63) / 64, NS2), 256, 0, stream>>>(
        q2, k2, v2, N2, NP2, CH2, l2, a2p);
    combine_kernel<<<dim3((N2 + 255) / 256, 4), 256, 0, stream>>>(
        a2p, l2, NS2, N2, 64, a2g, p2, ao2);

    // ---- FC [246016] -> [50]
    fc_partial_kernel<<<dim3(32, 50), 256, 0, stream>>>(ao2, fcw, 64 * N2, 32, fcp);
    fc_final_kernel<<<1, 64, 0, stream>>>(fcp, fcb, 32, out);
}

// Round 6
// 297.885 us; speedup vs baseline: 2.0310x; 1.0442x over previous
//
#include <hip/hip_runtime.h>
#include <hip/hip_bf16.h>

typedef float f32x4 __attribute__((ext_vector_type(4)));
typedef short bf16x4 __attribute__((ext_vector_type(4)));
typedef unsigned short u16x4 __attribute__((ext_vector_type(4)));
typedef unsigned short u16x8 __attribute__((ext_vector_type(8)));

__device__ inline unsigned short f2bf(float x) {
    __hip_bfloat16 h = __float2bfloat16(x);
    return *reinterpret_cast<unsigned short*>(&h);
}

__device__ inline int cvt_pk_bf16(float a, float b) {
    int r;
    asm("v_cvt_pk_bf16_f32 %0, %1, %2" : "=v"(r) : "v"(a), "v"(b));
    return r;
}

// ---------------------------------------------------------------------------
// Register-tiled 3x3 VALID conv (stride 1) + fused BN-sum reduction.
// Block = 256 threads; each thread computes a 1x4 output strip.
// ---------------------------------------------------------------------------
template <int CIN, int ICB>
__launch_bounds__(256)
__global__ void conv3x3_rt_kernel(const float* __restrict__ src, int H, int W,
                                  const float* __restrict__ w,
                                  const float* __restrict__ b,
                                  float* __restrict__ dst, int OH, int OW,
                                  float* __restrict__ bn_accum) {
    __shared__ __align__(16) float xs[ICB][18][68];
    __shared__ __align__(16) float wsm[ICB][12];
    __shared__ float red[512];

    const int oc  = blockIdx.z;
    const int ox0 = blockIdx.x * 64;
    const int oy0 = blockIdx.y * 16;
    const int tid = threadIdx.x;
    const int ty  = tid >> 4;
    const int tx  = (tid & 15) << 2;

    float o0, o1, o2, o3;
    o0 = o1 = o2 = o3 = b[oc];

    const int scol   = tid & 63;
    const int sslot0 = tid >> 6;
    const bool colok = (ox0 + scol) < W;

    for (int icb = 0; icb < CIN; icb += ICB) {
        __syncthreads();
        {
            int s  = sslot0;
            int rr = sslot0;
            const float* gp = src + ((size_t)icb * H + oy0 + rr) * W + ox0 + scol;
            float* lp = &xs[0][0][0] + (size_t)s * 68 + scol;
            while (s < ICB * 18) {
                int y = oy0 + rr;
                *lp = (y < H && colok) ? *gp : 0.f;
                s += 4; rr += 4;
                gp += 4 * (size_t)W;
                lp += 4 * 68;
                if (rr >= 18) { rr -= 18; gp += ((size_t)H - 18) * W; }
            }
        }
        if (tid < ICB * 18) {
            int c = tid / 18, r = tid - c * 18;
            int y = oy0 + r;
            const float* gp = src + ((size_t)(icb + c) * H + y) * W + ox0 + 64;
            bool yok = (y < H);
            xs[c][r][64] = (yok && (ox0 + 64) < W) ? gp[0] : 0.f;
            xs[c][r][65] = (yok && (ox0 + 65) < W) ? gp[1] : 0.f;
        }
        if (tid < ICB * 9) {
            int c = tid / 9, j = tid - c * 9;
            wsm[c][j] = w[((size_t)oc * CIN + icb + c) * 9 + j];
        }
        __syncthreads();

        #pragma unroll
        for (int c = 0; c < ICB; ++c) {
            float wv[9];
            #pragma unroll
            for (int j = 0; j < 9; ++j) wv[j] = wsm[c][j];
            #pragma unroll
            for (int kh = 0; kh < 3; ++kh) {
                const float* xp = &xs[c][ty + kh][tx];
                f32x4 x03 = *(const f32x4*)xp;
                float x4 = xp[4], x5 = xp[5];
                const float w0 = wv[kh * 3], w1 = wv[kh * 3 + 1], w2 = wv[kh * 3 + 2];
                o0 = fmaf(x03[0], w0, o0); o0 = fmaf(x03[1], w1, o0); o0 = fmaf(x03[2], w2, o0);
                o1 = fmaf(x03[1], w0, o1); o1 = fmaf(x03[2], w1, o1); o1 = fmaf(x03[3], w2, o1);
                o2 = fmaf(x03[2], w0, o2); o2 = fmaf(x03[3], w1, o2); o2 = fmaf(x4,     w2, o2);
                o3 = fmaf(x03[3], w0, o3); o3 = fmaf(x4,     w1, o3); o3 = fmaf(x5,     w2, o3);
            }
        }
    }

    const int oy = oy0 + ty;
    const int ox = ox0 + tx;
    float s1 = 0.f, s2 = 0.f;
    if (oy < OH) {
        float* dp = dst + ((size_t)oc * OH + oy) * OW + ox;
        if (ox + 0 < OW) { dp[0] = o0; s1 += o0; s2 = fmaf(o0, o0, s2); }
        if (ox + 1 < OW) { dp[1] = o1; s1 += o1; s2 = fmaf(o1, o1, s2); }
        if (ox + 2 < OW) { dp[2] = o2; s1 += o2; s2 = fmaf(o2, o2, s2); }
        if (ox + 3 < OW) { dp[3] = o3; s1 += o3; s2 = fmaf(o3, o3, s2); }
    }
    red[tid]       = s1;
    red[256 + tid] = s2;
    __syncthreads();
    for (int off2 = 128; off2 > 0; off2 >>= 1) {
        if (tid < off2) {
            red[tid]       += red[tid + off2];
            red[256 + tid] += red[256 + tid + off2];
        }
        __syncthreads();
    }
    if (tid == 0) {
        atomicAdd(&bn_accum[oc * 2],     red[0]);
        atomicAdd(&bn_accum[oc * 2 + 1], red[256]);
    }
}

// ---------------------------------------------------------------------------
__global__ void bn_final_kernel(const float* __restrict__ sums, int C, int spatial,
                                const float* __restrict__ g, const float* __restrict__ bb,
                                float* __restrict__ inv_shift) {
    int c = threadIdx.x;
    if (c >= C) return;
    float m   = sums[c * 2] / (float)spatial;
    float var = sums[c * 2 + 1] / (float)spatial - m * m;
    float inv = g[c] * rsqrtf(var + 1e-5f);
    inv_shift[c * 2]     = inv;
    inv_shift[c * 2 + 1] = bb[c] - m * inv;
}

// ---------------------------------------------------------------------------
__global__ void bn_pool_kernel(const float* __restrict__ src,
                               const float* __restrict__ inv_shift,
                               int H, int W, int OH, int OW, int C,
                               float* __restrict__ dst) {
    int i = blockIdx.x * blockDim.x + threadIdx.x;
    if (i >= C * OH * OW) return;
    int ox = i % OW;
    int oy = (i / OW) % OH;
    int c  = i / (OW * OH);
    float inv = inv_shift[c * 2], sh = inv_shift[c * 2 + 1];
    const float* p = src + ((size_t)c * H + 2 * oy) * W + 2 * ox;
    float a = fmaxf(fmaf(p[0],     inv, sh), 0.f);
    float b = fmaxf(fmaf(p[1],     inv, sh), 0.f);
    float d = fmaxf(fmaf(p[W],     inv, sh), 0.f);
    float e = fmaxf(fmaf(p[W + 1], inv, sh), 0.f);
    dst[i] = fmaxf(fmaxf(a, b), fmaxf(d, e));
}

// ---------------------------------------------------------------------------
// 1x1-conv QKV projection.
// q,k -> n-major bf16 [NP][Cqk] (q pre-scaled by log2e); v -> bf16 [ch][NP].
// ---------------------------------------------------------------------------
__global__ void qkv_proj_kernel(const float* __restrict__ xf, int N, int NP, int C, int Cqk,
                                const float* __restrict__ qw, const float* __restrict__ qb,
                                const float* __restrict__ kw, const float* __restrict__ kb,
                                const float* __restrict__ vw, const float* __restrict__ vb,
                                unsigned short* __restrict__ qo,
                                unsigned short* __restrict__ ko,
                                unsigned short* __restrict__ vo) {
    constexpr int OCG = 8;
    __shared__ float wl[OCG * 64 + OCG];
    const int g0 = blockIdx.y * OCG;
    const int tid = threadIdx.x;
    for (int i = tid; i < OCG * C; i += blockDim.x) {
        int o = i / C, cc = i % C;
        int oc = g0 + o;
        const float* wsrc = (oc < Cqk) ? (qw + oc * C)
                          : (oc < 2 * Cqk) ? (kw + (oc - Cqk) * C)
                          : (vw + (oc - 2 * Cqk) * C);
        wl[o * C + cc] = wsrc[cc];
    }
    if (tid < OCG) {
        int oc = g0 + tid;
        wl[OCG * C + tid] = (oc < Cqk) ? qb[oc]
                          : (oc < 2 * Cqk) ? kb[oc - Cqk]
                          : vb[oc - 2 * Cqk];
    }
    __syncthreads();
    int n = blockIdx.x * blockDim.x + tid;
    if (n >= N) return;
    float acc[OCG];
    #pragma unroll
    for (int o = 0; o < OCG; ++o) acc[o] = wl[OCG * C + o];
    for (int c = 0; c < C; ++c) {
        float xv = xf[(size_t)c * N + n];
        #pragma unroll
        for (int o = 0; o < OCG; ++o) acc[o] = fmaf(xv, wl[o * C + c], acc[o]);
    }
    const float LOG2E = 1.44269504f;
    if (g0 < 2 * Cqk) {
        if (Cqk == 4) {                  // group 0: acc[0..3]=q, acc[4..7]=k
            u16x4 qs, ks;
            #pragma unroll
            for (int j = 0; j < 4; ++j) {
                qs[j] = f2bf(acc[j] * LOG2E);
                ks[j] = f2bf(acc[4 + j]);
            }
            *(u16x4*)&qo[(size_t)n * 4] = qs;
            *(u16x4*)&ko[(size_t)n * 4] = ks;
        } else {                         // Cqk==8: group 0 = q, group 1 = k
            unsigned short* dst = (g0 == 0) ? qo : ko;
            float sc = (g0 == 0) ? LOG2E : 1.f;
            u16x4 a, bb2;
            #pragma unroll
            for (int j = 0; j < 4; ++j) {
                a[j]   = f2bf(acc[j] * sc);
                bb2[j] = f2bf(acc[4 + j] * sc);
            }
            *(u16x4*)&dst[(size_t)n * 8]     = a;
            *(u16x4*)&dst[(size_t)n * 8 + 4] = bb2;
        }
    } else {
        #pragma unroll
        for (int o = 0; o < OCG; ++o)
            vo[(size_t)(g0 + o - 2 * Cqk) * NP + n] = f2bf(acc[o]);
    }
}

// ---------------------------------------------------------------------------
// Flash attention v4: QK^T AND PV on 16x16x16 bf16 MFMA, zero cross-lane fixup.
// Swapped QK (mfma(K,Q)): lane(g,q) gets E[key=16t+4g+r][q] in D-frags, which
// is exactly the A-frag (k-slots 4g+j) for the PV 16x16x16 MFMA of key-tile t.
// K,Q: n-major bf16 [NP][CQK], read direct from global (L2-resident, 16 lanes
// = 128B contiguous). Q pre-scaled by log2e; p = exp2(E). B-frag k-slots >=
// CQK zeroed so don't-care A slots can't inject NaN. V: bf16 [CV][NP], staged
// in double-buffered LDS (stride 72) with reg prefetch; ONE barrier per chunk.
// D accum: ch = lane&15, query = qb + 4g + reg. Split partials as before.
// ---------------------------------------------------------------------------
template <int CQK, int CV>
__launch_bounds__(256)
__global__ void flash_mfma_kernel(const unsigned short* __restrict__ qbf,
                                  const unsigned short* __restrict__ kbf,
                                  const unsigned short* __restrict__ v,
                                  int N, int NP, int chunk,
                                  float* __restrict__ l_part,
                                  float* __restrict__ acc_part) {
    constexpr int VS = 72;
    __shared__ unsigned short vsm[2][CV * VS];
    const int tid  = threadIdx.x;
    const int wave = tid >> 6;
    const int lane = tid & 63;
    const int lq   = lane & 15;     // query col (D) / A-frag row
    const int g    = lane >> 4;
    const int s    = blockIdx.y;
    const int m0   = s * chunk;
    const int m1   = min(N, m0 + chunk);
    const int qb   = blockIdx.x * 64 + wave * 16;
    const int n    = qb + lq;

    // Q B-frag: lane(g,q) supplies Q[ch = 4g+j][query q]; zero for ch >= CQK
    bf16x4 qf = (bf16x4){0, 0, 0, 0};
    if (g * 4 < CQK)
        qf = *(const bf16x4*)&qbf[(size_t)n * CQK + 4 * g];

    // V staging coords
    const int vch = tid >> 3;            // 0..31
    const int vkk = (tid & 7) * 8;       // 0..56

    f32x4 acc[CV / 16];
    #pragma unroll
    for (int f = 0; f < CV / 16; ++f) acc[f] = (f32x4){0.f, 0.f, 0.f, 0.f};
    float lsum = 0.f;

    const int nch = (m1 - m0 + 63) >> 6;

    u16x8 vreg[CV / 32];
    #pragma unroll
    for (int vv = 0; vv < CV / 32; ++vv)
        vreg[vv] = *(const u16x8*)&v[(size_t)(vch + 32 * vv) * NP + m0 + vkk];
    #pragma unroll
    for (int vv = 0; vv < CV / 32; ++vv)
        *(u16x8*)&vsm[0][(vch + 32 * vv) * VS + vkk] = vreg[vv];
    __syncthreads();

    for (int t = 0; t < nch; ++t) {
        const int mt  = m0 + t * 64;
        const int cur = t & 1;
        const int mtn = (t + 1 < nch) ? mt + 64 : mt;
        #pragma unroll
        for (int vv = 0; vv < CV / 32; ++vv)
            vreg[vv] = *(const u16x8*)&v[(size_t)(vch + 32 * vv) * NP + mtn + vkk];

        // K A-frags: lane(g,q) supplies K[key=16t'+q][ch 4g+j]; don't-care
        // slots must be finite -> zero-init, predicated load
        bf16x4 kf[4];
        #pragma unroll
        for (int tt = 0; tt < 4; ++tt) {
            kf[tt] = (bf16x4){0, 0, 0, 0};
            if (g * 4 < CQK)
                kf[tt] = *(const bf16x4*)&kbf[(size_t)(mt + 16 * tt + lq) * CQK + 4 * g];
        }
        f32x4 e[4];
        #pragma unroll
        for (int tt = 0; tt < 4; ++tt)
            e[tt] = __builtin_amdgcn_mfma_f32_16x16x16bf16_1k(
                kf[tt], qf, (f32x4){0.f, 0.f, 0.f, 0.f}, 0, 0, 0);

        bf16x4 pf[4];
        const bool tail = (mt + 64 > m1);
        if (!tail) {
            #pragma unroll
            for (int tt = 0; tt < 4; ++tt) {
                float p0 = exp2f(e[tt][0]), p1 = exp2f(e[tt][1]);
                float p2 = exp2f(e[tt][2]), p3 = exp2f(e[tt][3]);
                lsum += (p0 + p1) + (p2 + p3);
                int2 pi;
                pi.x = cvt_pk_bf16(p0, p1);
                pi.y = cvt_pk_bf16(p2, p3);
                pf[tt] = __builtin_bit_cast(bf16x4, pi);
            }
        } else {
            #pragma unroll
            for (int tt = 0; tt < 4; ++tt) {
                int key = mt + 16 * tt + 4 * g;
                float p0 = (key + 0 < m1) ? exp2f(e[tt][0]) : 0.f;
                float p1 = (key + 1 < m1) ? exp2f(e[tt][1]) : 0.f;
                float p2 = (key + 2 < m1) ? exp2f(e[tt][2]) : 0.f;
                float p3 = (key + 3 < m1) ? exp2f(e[tt][3]) : 0.f;
                lsum += (p0 + p1) + (p2 + p3);
                int2 pi;
                pi.x = cvt_pk_bf16(p0, p1);
                pi.y = cvt_pk_bf16(p2, p3);
                pf[tt] = __builtin_bit_cast(bf16x4, pi);
            }
        }

        // PV: A = P (k-slots 4g+j = this lane's keys), B = V^T from LDS
        #pragma unroll
        for (int tt = 0; tt < 4; ++tt) {
            #pragma unroll
            for (int f = 0; f < CV / 16; ++f) {
                bf16x4 vf = *(const bf16x4*)&vsm[cur][(f * 16 + lq) * VS + 16 * tt + 4 * g];
                acc[f] = __builtin_amdgcn_mfma_f32_16x16x16bf16_1k(pf[tt], vf, acc[f], 0, 0, 0);
            }
        }

        // write next chunk's V into the other buffer, then single barrier
        #pragma unroll
        for (int vv = 0; vv < CV / 32; ++vv)
            *(u16x8*)&vsm[cur ^ 1][(vch + 32 * vv) * VS + vkk] = vreg[vv];
        __syncthreads();
    }

    lsum += __shfl_xor(lsum, 16, 64);
    lsum += __shfl_xor(lsum, 32, 64);
    if (g == 0 && n < N) l_part[(size_t)s * N + n] = lsum;

    #pragma unroll
    for (int f = 0; f < CV / 16; ++f) {
        #pragma unroll
        for (int r2 = 0; r2 < 4; ++r2) {
            int nq = qb + 4 * g + r2;
            if (nq < N)
                acc_part[((size_t)s * N + nq) * CV + f * 16 + lq] = acc[f][r2];
        }
    }
}

// ---------------------------------------------------------------------------
__global__ void combine_kernel(const float* __restrict__ acc_part,
                               const float* __restrict__ l_part,
                               int nsplit, int N, int CV,
                               const float* __restrict__ gamma,
                               const float* __restrict__ x_res,
                               float* __restrict__ out) {
    int n = blockIdx.x * blockDim.x + threadIdx.x;
    if (n >= N) return;
    int cv0 = blockIdx.y * 16;
    float l = 0.f;
    for (int s = 0; s < nsplit; ++s) l += l_part[(size_t)s * N + n];
    f32x4 a[4];
    #pragma unroll
    for (int t = 0; t < 4; ++t) a[t] = (f32x4){0.f, 0.f, 0.f, 0.f};
    for (int s = 0; s < nsplit; ++s) {
        const float* p = acc_part + ((size_t)s * N + n) * CV + cv0;
        #pragma unroll
        for (int t = 0; t < 4; ++t) a[t] += *(const f32x4*)(p + 4 * t);
    }
    float gs = gamma[0] / l;
    #pragma unroll
    for (int t = 0; t < 4; ++t)
        #pragma unroll
        for (int u = 0; u < 4; ++u) {
            int cv = cv0 + 4 * t + u;
            out[(size_t)cv * N + n] = fmaf(gs, a[t][u], x_res[(size_t)cv * N + n]);
        }
}

// ---------------------------------------------------------------------------
__global__ void fc_partial_kernel(const float* __restrict__ h, const float* __restrict__ w,
                                  int K, int nchunk, float* __restrict__ partial) {
    const int r = blockIdx.y, cb = blockIdx.x;
    const int chunk = K / nchunk;
    const int j0 = cb * chunk;
    const int j1 = (cb == nchunk - 1) ? K : j0 + chunk;
    const float* wr = w + (size_t)r * K;
    float s = 0.f;
    for (int j = j0 + (int)threadIdx.x * 4; j + 3 < j1; j += blockDim.x * 4) {
        float4 hv = *reinterpret_cast<const float4*>(h + j);
        float4 wv = *reinterpret_cast<const float4*>(wr + j);
        s += hv.x * wv.x + hv.y * wv.y + hv.z * wv.z + hv.w * wv.w;
    }
    __shared__ float red[256];
    red[threadIdx.x] = s;
    __syncthreads();
    for (int off = 128; off > 0; off >>= 1) {
        if ((int)threadIdx.x < off) red[threadIdx.x] += red[threadIdx.x + off];
        __syncthreads();
    }
    if (threadIdx.x == 0) partial[r * gridDim.x + cb] = red[0];
}

__global__ void fc_final_kernel(const float* __restrict__ partial,
                                const float* __restrict__ b, int nchunk,
                                float* __restrict__ out) {
    int r = threadIdx.x;
    if (r < 50) {
        float s = b[r];
        for (int i = 0; i < nchunk; ++i) s += partial[r * nchunk + i];
        out[r] = s;
    }
}

// ---------------------------------------------------------------------------
extern "C" void kernel_launch(void* const* d_in, const int* in_sizes, int n_in,
                              void* d_out, int out_size, void* d_ws, size_t ws_size,
                              hipStream_t stream) {
    const float* x    = (const float*)d_in[0];
    const float* c1w  = (const float*)d_in[1];
    const float* c1b  = (const float*)d_in[2];
    const float* bn1g = (const float*)d_in[3];
    const float* bn1b = (const float*)d_in[4];
    const float* a1qw = (const float*)d_in[5];
    const float* a1qb = (const float*)d_in[6];
    const float* a1kw = (const float*)d_in[7];
    const float* a1kb = (const float*)d_in[8];
    const float* a1vw = (const float*)d_in[9];
    const float* a1vb = (const float*)d_in[10];
    const float* a1g  = (const float*)d_in[11];
    const float* c2w  = (const float*)d_in[12];
    const float* c2b  = (const float*)d_in[13];
    const float* bn2g = (const float*)d_in[14];
    const float* bn2b = (const float*)d_in[15];
    const float* a2qw = (const float*)d_in[16];
    const float* a2qb = (const float*)d_in[17];
    const float* a2kw = (const float*)d_in[18];
    const float* a2kb = (const float*)d_in[19];
    const float* a2vw = (const float*)d_in[20];
    const float* a2vb = (const float*)d_in[21];
    const float* a2g  = (const float*)d_in[22];
    const float* fcw  = (const float*)d_in[23];
    const float* fcb  = (const float*)d_in[24];
    float* out = (float*)d_out;

    const int N1 = 127 * 127;            // 16129
    const int N2 = 62 * 62;              // 3844
    const int NP1 = (N1 + 63) & ~63;     // 16192
    const int NP2 = (N2 + 63) & ~63;     // 3904
    const int NS1 = 4, NS2 = 16;
    const int CH1 = ((N1 + NS1 - 1) / NS1 + 63) & ~63;   // 4064
    const int CH2 = ((N2 + NS2 - 1) / NS2 + 63) & ~63;   // 256

    char* base = (char*)d_ws;
    size_t off = 0;
    auto alloc = [&](size_t bytes) {
        void* p = base + off;
        off += (bytes + 63) & ~(size_t)63;
        return p;
    };
    float* h1     = (float*)alloc(sizeof(float) * 32 * 254 * 254);
    float* bnSums = (float*)alloc(sizeof(float) * 256);
    float* bnA    = (float*)alloc(sizeof(float) * 64);
    float* p1     = (float*)alloc(sizeof(float) * 32 * N1);
    unsigned short* q1 = (unsigned short*)alloc(sizeof(short) * NP1 * 4);
    unsigned short* k1 = (unsigned short*)alloc(sizeof(short) * NP1 * 4);
    unsigned short* v1 = (unsigned short*)alloc(sizeof(short) * 32 * NP1);
    float* l1     = (float*)alloc(sizeof(float) * NS1 * N1);
    float* a1p    = (float*)alloc(sizeof(float) * (size_t)NS1 * N1 * 32);
    float* ao1    = (float*)alloc(sizeof(float) * 32 * N1);
    float* h2     = (float*)alloc(sizeof(float) * 64 * 125 * 125);
    float* bnB    = (float*)alloc(sizeof(float) * 128);
    float* p2     = (float*)alloc(sizeof(float) * 64 * N2);
    unsigned short* q2 = (unsigned short*)alloc(sizeof(short) * NP2 * 8);
    unsigned short* k2 = (unsigned short*)alloc(sizeof(short) * NP2 * 8);
    unsigned short* v2 = (unsigned short*)alloc(sizeof(short) * 64 * NP2);
    float* l2     = (float*)alloc(sizeof(float) * NS2 * N2);
    float* a2p    = (float*)alloc(sizeof(float) * (size_t)NS2 * N2 * 64);
    float* ao2    = (float*)alloc(sizeof(float) * 64 * N2);
    float* fcp    = (float*)alloc(sizeof(float) * 2048);

    hipMemsetAsync(bnSums, 0, 256 * sizeof(float), stream);

    // ---- stage 1: conv1 [3,256,256] -> [32,254,254] (+BN sums)
    conv3x3_rt_kernel<3, 3><<<dim3(4, 16, 32), 256, 0, stream>>>(
        x, 256, 256, c1w, c1b, h1, 254, 254, bnSums);
    bn_final_kernel<<<1, 32, 0, stream>>>(bnSums, 32, 254 * 254, bn1g, bn1b, bnA);
    bn_pool_kernel<<<(32 * N1 + 255) / 256, 256, 0, stream>>>(
        h1, bnA, 254, 254, 127, 127, 32, p1);

    // ---- attention 1 (C=32, Cqk=4, N=16129)
    qkv_proj_kernel<<<dim3((N1 + 255) / 256, 5), 256, 0, stream>>>(
        p1, N1, NP1, 32, 4, a1qw, a1qb, a1kw, a1kb, a1vw, a1vb, q1, k1, v1);
    flash_mfma_kernel<4, 32><<<dim3((N1 + 63) / 64, NS1), 256, 0, stream>>>(
        q1, k1, v1, N1, NP1, CH1, l1, a1p);
    combine_kernel<<<dim3((N1 + 255) / 256, 2), 256, 0, stream>>>(
        a1p, l1, NS1, N1, 32, a1g, p1, ao1);

    // ---- stage 2: conv2 [32,127,127] -> [64,125,125] (+BN sums)
    conv3x3_rt_kernel<32, 8><<<dim3(2, 8, 64), 256, 0, stream>>>(
        ao1, 127, 127, c2w, c2b, h2, 125, 125, bnSums + 64);
    bn_final_kernel<<<1, 64, 0, stream>>>(bnSums + 64, 64, 125 * 125, bn2g, bn2b, bnB);
    bn_pool_kernel<<<(64 * N2 + 255) / 256, 256, 0, stream>>>(
        h2, bnB, 125, 125, 62, 62, 64, p2);

    // ---- attention 2 (C=64, Cqk=8, N=3844)
    qkv_proj_kernel<<<dim3((N2 + 255) / 256, 10), 256, 0, stream>>>(
        p2, N2, NP2, 64, 8, a2qw, a2qb, a2kw, a2kb, a2vw, a2vb, q2, k2, v2);
    flash_mfma_kernel<8, 64><<<dim3((N2 + 63) / 64, NS2), 256, 0, stream>>>(
        q2, k2, v2, N2, NP2, CH2, l2, a2p);
    combine_kernel<<<dim3((N2 + 255) / 256, 4), 256, 0, stream>>>(
        a2p, l2, NS2, N2, 64, a2g, p2, ao2);

    // ---- FC [246016] -> [50]
    fc_partial_kernel<<<dim3(32, 50), 256, 0, stream>>>(ao2, fcw, 64 * N2, 32, fcp);
    fc_final_kernel<<<1, 64, 0, stream>>>(fcp, fcb, 32, out);
}